// Round 11
// baseline (438.652 us; speedup 1.0000x reference)
//
#include <hip/hip_runtime.h>
#include <hip/hip_bf16.h>

#define VOCAB 512
#define EMB   128
#define HID   64
#define BATCH 256
#define TLEN  1024
#define CH    16              // steps per chunk
#define NCH   (TLEN / CH)     // 64 chunks
#define RS    128             // p1 ring depth in steps
#define RCH   (RS / CH)       // 8 chunks per ring

typedef float v2f __attribute__((ext_vector_type(2)));

__device__ __forceinline__ float fast_tanh(float x) {
    // tanh(x) = 1 - 2/(exp(2x)+1); exact at both saturated ends.
    float e = __expf(2.0f * x);
    return 1.0f - 2.0f / (e + 1.0f);
}

__device__ __forceinline__ void lds_fence() {
    asm volatile("s_waitcnt lgkmcnt(0)" ::: "memory");
}
__device__ __forceinline__ void compiler_fence() {
    asm volatile("" ::: "memory");
}
__device__ __forceinline__ void nap() { __builtin_amdgcn_s_sleep(1); }

// Single-dot version (wave1 / epilogue): identical chain order to R8.
__device__ __forceinline__ float dot64_lds(const float4* hp, const v2f* w,
                                           float init) {
    v2f a0 = v2f{init, 0.f}, a1 = v2f{0.f, 0.f};
    v2f a2 = v2f{0.f, 0.f},  a3 = v2f{0.f, 0.f};
    #pragma unroll
    for (int q = 0; q < 8; ++q) {
        float4 u = hp[2 * q];
        float4 v = hp[2 * q + 1];
        a0 = __builtin_elementwise_fma(v2f{u.x, u.y}, w[4 * q + 0], a0);
        a1 = __builtin_elementwise_fma(v2f{u.z, u.w}, w[4 * q + 1], a1);
        a2 = __builtin_elementwise_fma(v2f{v.x, v.y}, w[4 * q + 2], a2);
        a3 = __builtin_elementwise_fma(v2f{v.z, v.w}, w[4 * q + 3], a3);
    }
    return ((a0.x + a0.y) + (a1.x + a1.y)) + ((a2.x + a2.y) + (a3.x + a3.y));
}

// ---------------------------------------------------------------------------
// Kernel 1: P0[v][i] = sum_e emb[v][e]*Wih0[i][e] + bih0[i] + bhh0[i]  (fp32)
// ---------------------------------------------------------------------------
__global__ void __launch_bounds__(64) p0_kernel(
    const float* __restrict__ emb,
    const float* __restrict__ wih0,
    const float* __restrict__ bih0,
    const float* __restrict__ bhh0,
    float* __restrict__ P0)
{
    const int v = blockIdx.x;
    const int i = threadIdx.x;
    const float4* er = (const float4*)(emb  + v * EMB);
    const float4* wr = (const float4*)(wih0 + i * EMB);
    float a0 = 0.f, a1 = 0.f, a2 = 0.f, a3 = 0.f;
    #pragma unroll
    for (int k = 0; k < EMB / 4; ++k) {
        float4 e4 = er[k];
        float4 w4 = wr[k];
        a0 = fmaf(e4.x, w4.x, a0);
        a1 = fmaf(e4.y, w4.y, a1);
        a2 = fmaf(e4.z, w4.z, a2);
        a3 = fmaf(e4.w, w4.w, a3);
    }
    P0[v * HID + i] = (a0 + a1) + (a2 + a3) + bih0[i] + bhh0[i];
}

// ---------------------------------------------------------------------------
// Kernel 2: TWO-WAVE pipeline. R10 post-mortem: R8 = 51 broadcast DS ops/step
// = exactly the shared-DS-pipe throughput wall (~14 cyc/op -> 737 cyc/step).
// Fix: wave0 holds BOTH Whh0 and Wih1 rows (128 fp32 regs) and computes the
// recurrence AND the projection from the SAME 16 broadcast reads (p1 lags one
// step, which is free). Wave1 of R8 is deleted: 36 DS ops/step, 2 contenders.
//   wave0: h0[t] = tanh(P0[x[t]] + Whh0 h0[t-1]);  p1[t-1] = b1 + Wih1 h0[t-1]
//   wave1: h1[t] = tanh(p1[t] + Whh1 h1[t-1]);  then the MLP head
// Registers kept lean (per-step +-2 prefetch, transient hv) to stay under the
// allocator's rematerialization cliff (R3/R4: ~200+ floats remats).
// ---------------------------------------------------------------------------
__global__ void __launch_bounds__(128, 1) rnn_kernel(
    const int*   __restrict__ xs,
    const float* __restrict__ P0,
    const float* __restrict__ Whh0,
    const float* __restrict__ Wih1,
    const float* __restrict__ Whh1,
    const float* __restrict__ bih1,
    const float* __restrict__ bhh1,
    const float* __restrict__ W1,
    const float* __restrict__ b1,
    const float* __restrict__ W2,
    const float* __restrict__ b2,
    float*       __restrict__ out)
{
    __shared__ float h0buf[2][HID];     // wave0's own recurrence buffer
    __shared__ float p1ring[RS][HID];   // 32 KiB  p1 handoff (w0 -> w1)
    __shared__ float h1buf[2][HID];     // wave1's own recurrence buffer
    __shared__ int   flags[2];

    const int b    = blockIdx.x;
    const int tid  = threadIdx.x;
    const int wv   = tid >> 6;
    const int lane = tid & 63;

    const int* xrow = xs + b * TLEN;
    // vz == 0, opaque to uniformity analysis -> forces VECTOR loads (vmcnt)
    // for x reads instead of s_load (lgkmcnt) — keeps the DS counter clean.
    const int vz = (int)__builtin_amdgcn_mbcnt_lo(0u, 0u);

    if (wv == 0) {
        h0buf[0][lane] = 0.f;
        h0buf[1][lane] = 0.f;            // slot for h0[-1]
    } else {
        h1buf[0][lane] = 0.f;
        h1buf[1][lane] = 0.f;            // slot for h1[-1]
    }
    if (tid < 2) flags[tid] = 0;
    __syncthreads();                     // the ONLY barrier in the kernel

    volatile int* vf = (volatile int*)flags;

    if (wv == 0) {
        // ---- layer-0 recurrence + layer-1 input projection ----
        v2f w0[32], w1[32];              // Whh0 row & Wih1 row: 128 regs
        {
            const float4* r0 = (const float4*)(Whh0 + lane * HID);
            const float4* r1 = (const float4*)(Wih1 + lane * HID);
            #pragma unroll
            for (int k = 0; k < 16; ++k) {
                float4 u0 = r0[k], u1 = r1[k];
                w0[2 * k] = v2f{u0.x, u0.y}; w0[2 * k + 1] = v2f{u0.z, u0.w};
                w1[2 * k] = v2f{u1.x, u1.y}; w1[2 * k + 1] = v2f{u1.z, u1.w};
            }
        }
        const float b1s = bih1[lane] + bhh1[lane];

        // per-step +-2 P0 prefetch (R5 pattern, vector loads only)
        float a_pre = P0[(xrow[0 + vz] & (VOCAB - 1)) * HID + lane];
        float a_nxt = P0[(xrow[1 + vz] & (VOCAB - 1)) * HID + lane];
        int   xq    = xrow[2 + vz] & (VOCAB - 1);

        #pragma unroll 1
        for (int k = 0; k < NCH; ++k) {
            if (k >= RCH) {                       // p1 ring reuse guard
                while (vf[1] < k - (RCH - 1)) nap();
                compiler_fence();
            }
            #pragma unroll
            for (int i = 0; i < CH; ++i) {
                const int t = k * CH + i;
                // prefetch P0 row for t+2 (vmcnt only; never drained)
                float a_n2  = P0[xq * HID + lane];
                int   xq_n  = xrow[((t + 3 < TLEN) ? (t + 3) : (TLEN - 1)) + vz]
                              & (VOCAB - 1);
                // hv = broadcast h0[t-1]; feeds BOTH dots
                const float4* hp = (const float4*)h0buf[(t + 1) & 1];
                v2f c0 = v2f{a_pre, 0.f}, c1 = v2f{0.f, 0.f};
                v2f c2 = v2f{0.f, 0.f},   c3 = v2f{0.f, 0.f};
                v2f d0 = v2f{b1s, 0.f},   d1 = v2f{0.f, 0.f};
                v2f d2 = v2f{0.f, 0.f},   d3 = v2f{0.f, 0.f};
                #pragma unroll
                for (int q = 0; q < 8; ++q) {
                    float4 u = hp[2 * q];
                    float4 v = hp[2 * q + 1];
                    v2f uxy = v2f{u.x, u.y}, uzw = v2f{u.z, u.w};
                    v2f vxy = v2f{v.x, v.y}, vzw = v2f{v.z, v.w};
                    c0 = __builtin_elementwise_fma(uxy, w0[4 * q + 0], c0);
                    d0 = __builtin_elementwise_fma(uxy, w1[4 * q + 0], d0);
                    c1 = __builtin_elementwise_fma(uzw, w0[4 * q + 1], c1);
                    d1 = __builtin_elementwise_fma(uzw, w1[4 * q + 1], d1);
                    c2 = __builtin_elementwise_fma(vxy, w0[4 * q + 2], c2);
                    d2 = __builtin_elementwise_fma(vxy, w1[4 * q + 2], d2);
                    c3 = __builtin_elementwise_fma(vzw, w0[4 * q + 3], c3);
                    d3 = __builtin_elementwise_fma(vzw, w1[4 * q + 3], d3);
                }
                float z0 = ((c0.x + c0.y) + (c1.x + c1.y))
                         + ((c2.x + c2.y) + (c3.x + c3.y));
                float z1 = ((d0.x + d0.y) + (d1.x + d1.y))
                         + ((d2.x + d2.y) + (d3.x + d3.y));
                h0buf[t & 1][lane] = fast_tanh(z0);
                // p1[t-1] = b1 + Wih1 * h0[t-1]  (hv IS h0[t-1]).
                // t==0 writes garbage to slot RS-1; it is rewritten with the
                // real p1[RS-1] at t=RS before wave1 can read it (flag order).
                p1ring[(t - 1) & (RS - 1)][lane] = z1;
                // chunk k-1's p1 completes at i==0 (write of p1[k*CH-1])
                if (i == 0 && k > 0) {
                    lds_fence();                  // DS only, NOT vmcnt
                    if (lane == 0) vf[0] = k;
                }
                a_pre = a_nxt;
                a_nxt = a_n2;
                xq    = xq_n;
            }
        }
        // epilogue: p1[TLEN-1] from h0[TLEN-1]
        {
            const float4* hp = (const float4*)h0buf[(TLEN - 1) & 1];
            p1ring[(TLEN - 1) & (RS - 1)][lane] = dot64_lds(hp, w1, b1s);
            lds_fence();
            if (lane == 0) vf[0] = NCH;
        }
    } else {
        // ---- layer-1 recurrence + MLP head ----
        v2f w2[32];
        {
            const float4* r2 = (const float4*)(Whh1 + lane * HID);
            #pragma unroll
            for (int k = 0; k < 16; ++k) {
                float4 u = r2[k];
                w2[2 * k] = v2f{u.x, u.y}; w2[2 * k + 1] = v2f{u.z, u.w};
            }
        }
        #pragma unroll 1
        for (int k = 0; k < NCH; ++k) {
            while (vf[0] < k + 1) nap();
            compiler_fence();
            float p[CH];                           // bulk chunk read (DS)
            #pragma unroll
            for (int i = 0; i < CH; ++i)
                p[i] = p1ring[(k * CH + i) & (RS - 1)][lane];
            #pragma unroll
            for (int i = 0; i < CH; ++i) {
                const int t = k * CH + i;
                const float4* hp = (const float4*)h1buf[(t + 1) & 1];
                float z = dot64_lds(hp, w2, p[i]);
                h1buf[t & 1][lane] = fast_tanh(z);
            }
            lds_fence();                           // p1 reads consumed
            if (lane == 0) vf[1] = k + 1;
        }
        // ---- MLP head: y = relu(h1 @ W1^T + b1) @ W2^T + b2 ----
        lds_fence();
        const float* hN = h1buf[(TLEN - 1) & 1];
        float r = 0.f;
        if (lane < 32) {
            float acc = b1[lane];
            const float* w1r = W1 + lane * HID;
            #pragma unroll
            for (int j = 0; j < HID; ++j) acc = fmaf(w1r[j], hN[j], acc);
            r = fmaxf(acc, 0.f) * W2[lane];
        }
        #pragma unroll
        for (int off = 32; off > 0; off >>= 1) r += __shfl_down(r, off);
        if (lane == 0) out[b] = r + b2[0];
    }
}

extern "C" void kernel_launch(void* const* d_in, const int* in_sizes, int n_in,
                              void* d_out, int out_size, void* d_ws, size_t ws_size,
                              hipStream_t stream)
{
    const int*   x    = (const int*)d_in[0];
    const float* emb  = (const float*)d_in[1];
    const float* Wih0 = (const float*)d_in[2];
    const float* Whh0 = (const float*)d_in[3];
    const float* bih0 = (const float*)d_in[4];
    const float* bhh0 = (const float*)d_in[5];
    const float* Wih1 = (const float*)d_in[6];
    const float* Whh1 = (const float*)d_in[7];
    const float* bih1 = (const float*)d_in[8];
    const float* bhh1 = (const float*)d_in[9];
    const float* W1   = (const float*)d_in[10];
    const float* b1   = (const float*)d_in[11];
    const float* W2   = (const float*)d_in[12];
    const float* b2   = (const float*)d_in[13];

    float* P0 = (float*)d_ws;   // 512*64*4 = 128 KiB scratch

    hipLaunchKernelGGL(p0_kernel, dim3(VOCAB), dim3(HID), 0, stream,
                       emb, Wih0, bih0, bhh0, P0);
    hipLaunchKernelGGL(rnn_kernel, dim3(BATCH), dim3(128), 0, stream,
                       x, P0, Whh0, Wih1, Whh1, bih1, bhh1,
                       W1, b1, W2, b2, (float*)d_out);
}